// Round 1
// 990.927 us; speedup vs baseline: 1.8611x; 1.8611x over previous
//
#include <hip/hip_runtime.h>

// Batched complex QR (Householder, LAPACK clarfg/cgeqr2 convention).
// One batch element per wave; lane = matrix row (M=64 == wavefront size).
//
// v2 strategy (latency-bound fix):
//  * Main pass (qr_house_f32): factorization in FP32 with fast DPP-based
//    wave reductions (4 VALU dpp-adds + ds_swizzle(xor16) + ds_bpermute(xor32)
//    instead of 6 ds-swizzle butterfly stages). Q is formed by the exact
//    triangular solve Q = A * R^-1 (readlane broadcasts of R, per-lane FMAs,
//    no cross-lane reductions) instead of cung2r reflector replay.
//  * Sign robustness: LAPACK's sign decision is sign(Re(alpha_i)). FP32
//    accumulation error is <~1e-4; any batch where some |Re(alpha_i)| < 1e-2
//    is flagged (expected ~1% of batches) and fully redone by the proven
//    FP64 kernel (qr_house_f64, unchanged from the 1841us version) in a
//    second pass that early-exits on unflagged batches.

constexpr int Mrows = 64;
constexpr int Rcols = 16;

// ---------------- fast fp32 wave-64 sum-broadcast ----------------
// Stages 1-4 are DPP-fused VALU adds (no DS pipe, ~5cy each):
//   xor1 (quad_perm [1,0,3,2]), xor2 (quad_perm [2,3,0,1]),
//   fold 8-group (row_half_mirror), fold 16-group (row_mirror).
// Stage 5: ds_swizzle xor16 (1 DS op). Stage 6: ds_bpermute lane^32 (1 DS op).
template <int CTRL>
__device__ __forceinline__ float dpp_fadd(float v) {
  int s = __builtin_amdgcn_update_dpp(0, __float_as_int(v), CTRL, 0xF, 0xF, true);
  return v + __int_as_float(s);
}

__device__ __forceinline__ float wsum64f_fast(float v, int bpa) {
  v = dpp_fadd<0xB1>(v);   // quad_perm [1,0,3,2]  : + lane^1
  v = dpp_fadd<0x4E>(v);   // quad_perm [2,3,0,1]  : + lane^2
  v = dpp_fadd<0x141>(v);  // row_half_mirror      : + other quad in 8-group
  v = dpp_fadd<0x140>(v);  // row_mirror           : + other 8 in 16-group
  v += __int_as_float(__builtin_amdgcn_ds_swizzle(__float_as_int(v), 0x401F)); // + lane^16
  v += __int_as_float(__builtin_amdgcn_ds_bpermute(bpa, __float_as_int(v)));   // + lane^32
  return v;
}

__device__ __forceinline__ float rdlane(float v, int srclane) {
  return __int_as_float(__builtin_amdgcn_readlane(__float_as_int(v), srclane));
}

// ---------------- slow-path reductions (proven fp64 kernel) ----------------
__device__ __forceinline__ double wsum64d(double v) {
#pragma unroll
  for (int m = 32; m >= 1; m >>= 1) v += __shfl_xor(v, m, 64);
  return v;
}

__device__ __forceinline__ float wsum64f(float v) {
#pragma unroll
  for (int m = 32; m >= 1; m >>= 1) v += __shfl_xor(v, m, 64);
  return v;
}

// =====================================================================
// Pass 1: FP32 factorization + Q = A R^-1 solve. Flags risky batches.
// =====================================================================
__global__ __launch_bounds__(256) void qr_house_f32(
    const float* __restrict__ x, float* __restrict__ out,
    unsigned char* __restrict__ flags, int B) {
  const int lane = threadIdx.x & 63;
  const int wave = threadIdx.x >> 6;
  const int b = blockIdx.x * 4 + wave;
  if (b >= B) return;
  const int bpa = ((lane ^ 32) << 2);  // ds_bpermute byte addr for lane^32

  // Load row `lane` of batch b: 16 complex = 8 float4, contiguous per lane.
  const float4* xp = reinterpret_cast<const float4*>(
      x + (size_t)b * (Mrows * Rcols * 2) + (size_t)lane * (Rcols * 2));
  float xr[Rcols], xi[Rcols];   // original A (becomes Q in-place in the solve)
  float ar[Rcols], ai[Rcols];   // working copy -> R (upper) + reflectors (lower)
#pragma unroll
  for (int k = 0; k < Rcols / 2; ++k) {
    float4 t = xp[k];
    xr[2 * k] = t.x;  xi[2 * k] = t.y;
    xr[2 * k + 1] = t.z;  xi[2 * k + 1] = t.w;
  }
#pragma unroll
  for (int j = 0; j < Rcols; ++j) { ar[j] = xr[j]; ai[j] = xi[j]; }

  bool risky = false;

  // ---- cgeqr2 in fp32 (apply H_i^H = I - conj(tau) v v^H) ----
#pragma unroll
  for (int i = 0; i < Rcols; ++i) {
    float cr = ar[i], ci = ai[i];
    float sq = (lane > i) ? (cr * cr + ci * ci) : 0.0f;
    float xnorm2 = wsum64f_fast(sq, bpa);
    float alphr = rdlane(cr, i);
    float alphi = rdlane(ci, i);

    // Near-tie sign decision -> fp64 pass will redo this whole batch.
    risky = risky || (fabsf(alphr) < 1e-2f);

    float tr, ti;
    if (xnorm2 == 0.0f && alphi == 0.0f) {
      tr = 0.0f;  ti = 0.0f;
      // column already reduced; diagonal stays alpha (= ar[i] at lane i)
    } else {
      float nrm = sqrtf(alphr * alphr + alphi * alphi + xnorm2);
      float beta = (alphr >= 0.0f) ? -nrm : nrm;  // -SIGN(nrm, alphr)
      float rb = __builtin_amdgcn_rcpf(beta);
      tr = (beta - alphr) * rb;
      ti = -alphi * rb;
      float dr = alphr - beta, di = alphi;
      float inv = __builtin_amdgcn_rcpf(dr * dr + di * di);
      float sr = dr * inv, si = -di * inv;
      if (lane > i) {  // v = x / (alpha - beta), stored below diagonal
        ar[i] = cr * sr - ci * si;
        ai[i] = cr * si + ci * sr;
      }
      if (lane == i) {  // store R diagonal (real beta) for the solve
        ar[i] = beta;
        ai[i] = 0.0f;
      }
    }

    // v: v[i]=1, v[m>i]=stored, v[m<i]=0
    float vr = (lane == i) ? 1.0f : ((lane > i) ? ar[i] : 0.0f);
    float vi = (lane == i) ? 0.0f : ((lane > i) ? ai[i] : 0.0f);
    const float ctr = tr, cti = -ti;  // conj(tau)
#pragma unroll
    for (int j = i + 1; j < Rcols; ++j) {
      float pr = vr * ar[j] + vi * ai[j];
      float pi = vr * ai[j] - vi * ar[j];
      pr = wsum64f_fast(pr, bpa);
      pi = wsum64f_fast(pi, bpa);
      float wr = ctr * pr - cti * pi;
      float wi = ctr * pi + cti * pr;
      ar[j] -= wr * vr - wi * vi;
      ai[j] -= wr * vi + wi * vr;
    }
  }

  if (lane == 0) flags[b] = risky ? 1 : 0;
  if (risky) return;  // wave-uniform; fp64 pass produces this batch's output

  // ---- Q formation via triangular solve: Q[:,j] = (A[:,j] - sum_{k<j} Q[:,k] R[k,j]) / beta_j
  // R[k][j] lives in lane k of ar[j]/ai[j]; readlane broadcasts it (no reductions).
#pragma unroll
  for (int j = 0; j < Rcols; ++j) {
    float wr = xr[j], wi = xi[j];
#pragma unroll
    for (int k = 0; k < j; ++k) {
      float rr = rdlane(ar[j], k);
      float ri = rdlane(ai[j], k);
      wr -= xr[k] * rr - xi[k] * ri;
      wi -= xr[k] * ri + xi[k] * rr;
    }
    float rb = __builtin_amdgcn_rcpf(rdlane(ar[j], j));  // beta_j is real
    xr[j] = wr * rb;
    xi[j] = wi * rb;
  }

  float4* op = reinterpret_cast<float4*>(
      out + (size_t)b * (Mrows * Rcols * 2) + (size_t)lane * (Rcols * 2));
#pragma unroll
  for (int k = 0; k < Rcols / 2; ++k) {
    op[k] = make_float4(xr[2 * k], xi[2 * k], xr[2 * k + 1], xi[2 * k + 1]);
  }
}

// =====================================================================
// Pass 2: proven FP64 kernel (unchanged math), early-exit on clean batches.
// =====================================================================
__global__ __launch_bounds__(256) void qr_house_f64(
    const float* __restrict__ x, float* __restrict__ out,
    const unsigned char* __restrict__ flags, int B) {
  const int lane = threadIdx.x & 63;
  const int wave = threadIdx.x >> 6;
  const int b = blockIdx.x * 4 + wave;
  if (b >= B) return;
  if (flags && flags[b] == 0) return;

  const float4* xp = reinterpret_cast<const float4*>(
      x + (size_t)b * (Mrows * Rcols * 2) + (size_t)lane * (Rcols * 2));
  double ar[Rcols], ai[Rcols];
#pragma unroll
  for (int k = 0; k < Rcols / 2; ++k) {
    float4 t = xp[k];
    ar[2 * k] = (double)t.x;
    ai[2 * k] = (double)t.y;
    ar[2 * k + 1] = (double)t.z;
    ai[2 * k + 1] = (double)t.w;
  }

  double taur[Rcols], taui[Rcols];

#pragma unroll
  for (int i = 0; i < Rcols; ++i) {
    double cr = ar[i], ci = ai[i];
    double sq = (lane > i) ? (cr * cr + ci * ci) : 0.0;
    double xnorm2 = wsum64d(sq);
    double alphr = __shfl(cr, i, 64);
    double alphi = __shfl(ci, i, 64);

    double tr, ti;
    if (xnorm2 == 0.0 && alphi == 0.0) {
      tr = 0.0;
      ti = 0.0;
    } else {
      double nrm = sqrt(alphr * alphr + alphi * alphi + xnorm2);
      double beta = (alphr >= 0.0) ? -nrm : nrm;
      double rb = 1.0 / beta;
      tr = (beta - alphr) * rb;
      ti = -alphi * rb;
      double dr = alphr - beta, di = alphi;
      double inv = 1.0 / (dr * dr + di * di);
      double sr = dr * inv, si = -di * inv;
      if (lane > i) {
        double nr = cr * sr - ci * si;
        double ni = cr * si + ci * sr;
        ar[i] = nr;
        ai[i] = ni;
      }
    }
    taur[i] = tr;
    taui[i] = ti;

    double vr = (lane == i) ? 1.0 : ((lane > i) ? ar[i] : 0.0);
    double vi = (lane == i) ? 0.0 : ((lane > i) ? ai[i] : 0.0);
    const double ctr = tr, cti = -ti;
#pragma unroll
    for (int j = i + 1; j < Rcols; ++j) {
      double pr = vr * ar[j] + vi * ai[j];
      double pi = vr * ai[j] - vi * ar[j];
      pr = wsum64d(pr);
      pi = wsum64d(pi);
      double wr = ctr * pr - cti * pi;
      double wi = ctr * pi + cti * pr;
      ar[j] -= wr * vr - wi * vi;
      ai[j] -= wr * vi + wi * vr;
    }
  }

  float vfr[Rcols], vfi[Rcols], tfr[Rcols], tfi[Rcols];
#pragma unroll
  for (int i = 0; i < Rcols; ++i) {
    vfr[i] = (lane == i) ? 1.0f : ((lane > i) ? (float)ar[i] : 0.0f);
    vfi[i] = (lane == i) ? 0.0f : ((lane > i) ? (float)ai[i] : 0.0f);
    tfr[i] = (float)taur[i];
    tfi[i] = (float)taui[i];
  }

  float qre[Rcols], qim[Rcols];
#pragma unroll
  for (int i = Rcols - 1; i >= 0; --i) {
    const float tr = tfr[i], ti = tfi[i];
    const float vr = vfr[i], vi = vfi[i];
#pragma unroll
    for (int j = i + 1; j < Rcols; ++j) {
      float pr = vr * qre[j] + vi * qim[j];
      float pi = vr * qim[j] - vi * qre[j];
      pr = wsum64f(pr);
      pi = wsum64f(pi);
      float wr = tr * pr - ti * pi;
      float wi = tr * pi + ti * pr;
      qre[j] -= wr * vr - wi * vi;
      qim[j] -= wr * vi + wi * vr;
    }
    float dr = -(tr * vr - ti * vi);
    float di = -(tr * vi + ti * vr);
    if (lane == i) {
      dr = 1.0f - tr;
      di = -ti;
    }
    if (lane < i) {
      dr = 0.0f;
      di = 0.0f;
    }
    qre[i] = dr;
    qim[i] = di;
  }

  float4* op = reinterpret_cast<float4*>(
      out + (size_t)b * (Mrows * Rcols * 2) + (size_t)lane * (Rcols * 2));
#pragma unroll
  for (int k = 0; k < Rcols / 2; ++k) {
    op[k] = make_float4(qre[2 * k], qim[2 * k], qre[2 * k + 1], qim[2 * k + 1]);
  }
}

extern "C" void kernel_launch(void* const* d_in, const int* in_sizes, int n_in,
                              void* d_out, int out_size, void* d_ws,
                              size_t ws_size, hipStream_t stream) {
  const float* x = (const float*)d_in[0];
  float* out = (float*)d_out;
  const int B = in_sizes[0] / (Mrows * Rcols * 2);
  dim3 block(256);  // 4 waves -> 4 batch elements per block
  dim3 grid((B + 3) / 4);
  if (d_ws && ws_size >= (size_t)B) {
    unsigned char* flags = (unsigned char*)d_ws;
    qr_house_f32<<<grid, block, 0, stream>>>(x, out, flags, B);
    qr_house_f64<<<grid, block, 0, stream>>>(x, out, flags, B);
  } else {
    // No workspace for flags: run the proven fp64 kernel on everything.
    qr_house_f64<<<grid, block, 0, stream>>>(x, out, nullptr, B);
  }
}

// Round 2
// 721.585 us; speedup vs baseline: 2.5557x; 1.3733x over previous
//
#include <hip/hip_runtime.h>

// Batched complex QR (Householder, LAPACK clarfg/cgeqr2 convention).
// One batch element per wave; lane = matrix row (M=64 == wavefront size).
//
// v3 strategy:
//  * Main pass (qr_house_f32): FP32 factorization with pure-VALU wave
//    reductions (4 DPP-fused adds + permlane16_swap + permlane32_swap —
//    zero DS ops, no lgkmcnt stalls). Q formed by triangular solve
//    Q = A * R^-1 (readlane broadcasts, no reductions).
//  * Sign robustness: batches where any |Re(alpha_i)| < 1e-3 (fp32 alpha
//    error <~3e-5, 30x margin) are pushed onto a compacted worklist
//    (atomicAdd) and fully redone by the proven FP64 kernel, which
//    grid-strides over the worklist with 2048 waves (expected ~1.3% of
//    batches -> ~430 items -> ~1 item per active wave, dense occupancy).
//  * Round 1 post-mortem: flag-based redo at threshold 1e-2 flagged 12.7%
//    of batches (16 columns x 0.8%/col) and the scattered-wave sweep cost
//    414us; ds_swizzle/ds_bpermute chains kept the f32 pass at ~570us.

constexpr int Mrows = 64;
constexpr int Rcols = 16;

typedef int v2i __attribute__((ext_vector_type(2)));

// ---------------- fast fp32 wave-64 sum-broadcast (pure VALU) ----------------
// Stages 1-4: DPP-fused adds (xor1, xor2, fold-8, fold-16).
// Stage 5: v_permlane16_swap_b32(v, v) -> r0[l]=v[l|16], r1[l]=v[l&~16];
//          r0+r1 == v[l]+v[l^16].  Stage 6: same with permlane32 for ^32.
template <int CTRL>
__device__ __forceinline__ float dpp_fadd(float v) {
  int s = __builtin_amdgcn_update_dpp(0, __float_as_int(v), CTRL, 0xF, 0xF, true);
  return v + __int_as_float(s);
}

#if defined(__has_builtin)
#if __has_builtin(__builtin_amdgcn_permlane16_swap)
#define USE_PL16 1
#else
#define USE_PL16 0
#endif
#if __has_builtin(__builtin_amdgcn_permlane32_swap)
#define USE_PL32 1
#else
#define USE_PL32 0
#endif
#else
#define USE_PL16 0
#define USE_PL32 0
#endif

__device__ __forceinline__ float wsum64f_fast(float v, int bpa) {
  v = dpp_fadd<0xB1>(v);   // quad_perm [1,0,3,2]  : + lane^1
  v = dpp_fadd<0x4E>(v);   // quad_perm [2,3,0,1]  : + lane^2
  v = dpp_fadd<0x141>(v);  // row_half_mirror      : + other quad in 8-group
  v = dpp_fadd<0x140>(v);  // row_mirror           : + other 8 in 16-group
#if USE_PL16
  {
    v2i r = __builtin_amdgcn_permlane16_swap(__float_as_int(v), __float_as_int(v),
                                             false, false);
    v = __int_as_float(r[0]) + __int_as_float(r[1]);  // + lane^16
  }
#else
  v += __int_as_float(__builtin_amdgcn_ds_swizzle(__float_as_int(v), 0x401F));
#endif
#if USE_PL32
  {
    v2i r = __builtin_amdgcn_permlane32_swap(__float_as_int(v), __float_as_int(v),
                                             false, false);
    v = __int_as_float(r[0]) + __int_as_float(r[1]);  // + lane^32
  }
#else
  v += __int_as_float(__builtin_amdgcn_ds_bpermute(bpa, __float_as_int(v)));
#endif
  return v;
}

__device__ __forceinline__ float rdlane(float v, int srclane) {
  return __int_as_float(__builtin_amdgcn_readlane(__float_as_int(v), srclane));
}

// ---------------- slow-path reductions (proven fp64 kernel) ----------------
__device__ __forceinline__ double wsum64d(double v) {
#pragma unroll
  for (int m = 32; m >= 1; m >>= 1) v += __shfl_xor(v, m, 64);
  return v;
}

__device__ __forceinline__ float wsum64f(float v) {
#pragma unroll
  for (int m = 32; m >= 1; m >>= 1) v += __shfl_xor(v, m, 64);
  return v;
}

// =====================================================================
// Pass 1: FP32 factorization + Q = A R^-1 solve. Risky batches -> worklist.
// =====================================================================
__global__ __launch_bounds__(256) void qr_house_f32(
    const float* __restrict__ x, float* __restrict__ out,
    int* __restrict__ cnt, int* __restrict__ list,
    unsigned char* __restrict__ flags, int B) {
  const int lane = threadIdx.x & 63;
  const int wave = threadIdx.x >> 6;
  const int b = blockIdx.x * 4 + wave;
  if (b >= B) return;
  const int bpa = ((lane ^ 32) << 2);  // ds_bpermute fallback addr

  const float4* xp = reinterpret_cast<const float4*>(
      x + (size_t)b * (Mrows * Rcols * 2) + (size_t)lane * (Rcols * 2));
  float xr[Rcols], xi[Rcols];   // original A (becomes Q in the solve)
  float ar[Rcols], ai[Rcols];   // working copy -> R (upper) + reflectors
#pragma unroll
  for (int k = 0; k < Rcols / 2; ++k) {
    float4 t = xp[k];
    xr[2 * k] = t.x;  xi[2 * k] = t.y;
    xr[2 * k + 1] = t.z;  xi[2 * k + 1] = t.w;
  }
#pragma unroll
  for (int j = 0; j < Rcols; ++j) { ar[j] = xr[j]; ai[j] = xi[j]; }

  bool risky = false;

  // ---- cgeqr2 in fp32 (apply H_i^H = I - conj(tau) v v^H) ----
#pragma unroll
  for (int i = 0; i < Rcols; ++i) {
    float cr = ar[i], ci = ai[i];
    float sq = (lane > i) ? (cr * cr + ci * ci) : 0.0f;
    float xnorm2 = wsum64f_fast(sq, bpa);
    float alphr = rdlane(cr, i);
    float alphi = rdlane(ci, i);

    // Near-tie sign decision -> fp64 pass redoes this batch.
    // fp32 alpha error <~3e-5; 1e-3 keeps 30x margin, flags ~1.3% of batches.
    risky = risky || (fabsf(alphr) < 1e-3f);

    float tr, ti;
    if (xnorm2 == 0.0f && alphi == 0.0f) {
      tr = 0.0f;  ti = 0.0f;
    } else {
      float nrm = sqrtf(alphr * alphr + alphi * alphi + xnorm2);
      float beta = (alphr >= 0.0f) ? -nrm : nrm;  // -SIGN(nrm, alphr)
      float rb = __builtin_amdgcn_rcpf(beta);
      tr = (beta - alphr) * rb;
      ti = -alphi * rb;
      float dr = alphr - beta, di = alphi;
      float inv = __builtin_amdgcn_rcpf(dr * dr + di * di);
      float sr = dr * inv, si = -di * inv;
      if (lane > i) {  // v = x / (alpha - beta), stored below diagonal
        ar[i] = cr * sr - ci * si;
        ai[i] = cr * si + ci * sr;
      }
      if (lane == i) {  // R diagonal (real beta) for the solve
        ar[i] = beta;
        ai[i] = 0.0f;
      }
    }

    float vr = (lane == i) ? 1.0f : ((lane > i) ? ar[i] : 0.0f);
    float vi = (lane == i) ? 0.0f : ((lane > i) ? ai[i] : 0.0f);
    const float ctr = tr, cti = -ti;  // conj(tau)
#pragma unroll
    for (int j = i + 1; j < Rcols; ++j) {
      float pr = vr * ar[j] + vi * ai[j];
      float pi = vr * ai[j] - vi * ar[j];
      pr = wsum64f_fast(pr, bpa);
      pi = wsum64f_fast(pi, bpa);
      float wr = ctr * pr - cti * pi;
      float wi = ctr * pi + cti * pr;
      ar[j] -= wr * vr - wi * vi;
      ai[j] -= wr * vi + wi * vr;
    }
  }

  if (risky) {  // wave-uniform (alphr is broadcast)
    if (lane == 0) {
      if (cnt) {
        int idx = atomicAdd(cnt, 1);
        list[idx] = b;
      } else {
        flags[b] = 1;
      }
    }
    return;  // fp64 pass produces this batch's output
  }
  if (!cnt && lane == 0) flags[b] = 0;

  // ---- Q via triangular solve: Q[:,j] = (A[:,j] - sum_{k<j} Q[:,k] R[k,j]) / beta_j
  // R[k][j] lives in lane k of ar[j]/ai[j]; readlane broadcasts (no reductions).
#pragma unroll
  for (int j = 0; j < Rcols; ++j) {
    float wr = xr[j], wi = xi[j];
#pragma unroll
    for (int k = 0; k < j; ++k) {
      float rr = rdlane(ar[j], k);
      float ri = rdlane(ai[j], k);
      wr -= xr[k] * rr - xi[k] * ri;
      wi -= xr[k] * ri + xi[k] * rr;
    }
    float rb = __builtin_amdgcn_rcpf(rdlane(ar[j], j));  // beta_j is real
    xr[j] = wr * rb;
    xi[j] = wi * rb;
  }

  float4* op = reinterpret_cast<float4*>(
      out + (size_t)b * (Mrows * Rcols * 2) + (size_t)lane * (Rcols * 2));
#pragma unroll
  for (int k = 0; k < Rcols / 2; ++k) {
    op[k] = make_float4(xr[2 * k], xi[2 * k], xr[2 * k + 1], xi[2 * k + 1]);
  }
}

// =====================================================================
// FP64 redo: proven math (unchanged from the 1841us kernel), one batch.
// =====================================================================
__device__ void qr_f64_one(const float* __restrict__ x,
                           float* __restrict__ out, int b, int lane) {
  const float4* xp = reinterpret_cast<const float4*>(
      x + (size_t)b * (Mrows * Rcols * 2) + (size_t)lane * (Rcols * 2));
  double ar[Rcols], ai[Rcols];
#pragma unroll
  for (int k = 0; k < Rcols / 2; ++k) {
    float4 t = xp[k];
    ar[2 * k] = (double)t.x;
    ai[2 * k] = (double)t.y;
    ar[2 * k + 1] = (double)t.z;
    ai[2 * k + 1] = (double)t.w;
  }

  double taur[Rcols], taui[Rcols];

#pragma unroll
  for (int i = 0; i < Rcols; ++i) {
    double cr = ar[i], ci = ai[i];
    double sq = (lane > i) ? (cr * cr + ci * ci) : 0.0;
    double xnorm2 = wsum64d(sq);
    double alphr = __shfl(cr, i, 64);
    double alphi = __shfl(ci, i, 64);

    double tr, ti;
    if (xnorm2 == 0.0 && alphi == 0.0) {
      tr = 0.0;
      ti = 0.0;
    } else {
      double nrm = sqrt(alphr * alphr + alphi * alphi + xnorm2);
      double beta = (alphr >= 0.0) ? -nrm : nrm;
      double rb = 1.0 / beta;
      tr = (beta - alphr) * rb;
      ti = -alphi * rb;
      double dr = alphr - beta, di = alphi;
      double inv = 1.0 / (dr * dr + di * di);
      double sr = dr * inv, si = -di * inv;
      if (lane > i) {
        double nr = cr * sr - ci * si;
        double ni = cr * si + ci * sr;
        ar[i] = nr;
        ai[i] = ni;
      }
    }
    taur[i] = tr;
    taui[i] = ti;

    double vr = (lane == i) ? 1.0 : ((lane > i) ? ar[i] : 0.0);
    double vi = (lane == i) ? 0.0 : ((lane > i) ? ai[i] : 0.0);
    const double ctr = tr, cti = -ti;
#pragma unroll
    for (int j = i + 1; j < Rcols; ++j) {
      double pr = vr * ar[j] + vi * ai[j];
      double pi = vr * ai[j] - vi * ar[j];
      pr = wsum64d(pr);
      pi = wsum64d(pi);
      double wr = ctr * pr - cti * pi;
      double wi = ctr * pi + cti * pr;
      ar[j] -= wr * vr - wi * vi;
      ai[j] -= wr * vi + wi * vr;
    }
  }

  float vfr[Rcols], vfi[Rcols], tfr[Rcols], tfi[Rcols];
#pragma unroll
  for (int i = 0; i < Rcols; ++i) {
    vfr[i] = (lane == i) ? 1.0f : ((lane > i) ? (float)ar[i] : 0.0f);
    vfi[i] = (lane == i) ? 0.0f : ((lane > i) ? (float)ai[i] : 0.0f);
    tfr[i] = (float)taur[i];
    tfi[i] = (float)taui[i];
  }

  float qre[Rcols], qim[Rcols];
#pragma unroll
  for (int i = Rcols - 1; i >= 0; --i) {
    const float tr = tfr[i], ti = tfi[i];
    const float vr = vfr[i], vi = vfi[i];
#pragma unroll
    for (int j = i + 1; j < Rcols; ++j) {
      float pr = vr * qre[j] + vi * qim[j];
      float pi = vr * qim[j] - vi * qre[j];
      pr = wsum64f(pr);
      pi = wsum64f(pi);
      float wr = tr * pr - ti * pi;
      float wi = tr * pi + ti * pr;
      qre[j] -= wr * vr - wi * vi;
      qim[j] -= wr * vi + wi * vr;
    }
    float dr = -(tr * vr - ti * vi);
    float di = -(tr * vi + ti * vr);
    if (lane == i) {
      dr = 1.0f - tr;
      di = -ti;
    }
    if (lane < i) {
      dr = 0.0f;
      di = 0.0f;
    }
    qre[i] = dr;
    qim[i] = di;
  }

  float4* op = reinterpret_cast<float4*>(
      out + (size_t)b * (Mrows * Rcols * 2) + (size_t)lane * (Rcols * 2));
#pragma unroll
  for (int k = 0; k < Rcols / 2; ++k) {
    op[k] = make_float4(qre[2 * k], qim[2 * k], qre[2 * k + 1], qim[2 * k + 1]);
  }
}

// Pass 2 (worklist mode): 2048 waves grid-stride over the compacted list.
__global__ __launch_bounds__(256) void qr_house_f64_list(
    const float* __restrict__ x, float* __restrict__ out,
    const int* __restrict__ cnt, const int* __restrict__ list) {
  const int lane = threadIdx.x & 63;
  const int widx = blockIdx.x * 4 + (threadIdx.x >> 6);
  const int n = *cnt;
  for (int w = widx; w < n; w += 2048) {
    qr_f64_one(x, out, list[w], lane);
  }
}

// Pass 2 (flags fallback / full fallback).
__global__ __launch_bounds__(256) void qr_house_f64_flags(
    const float* __restrict__ x, float* __restrict__ out,
    const unsigned char* __restrict__ flags, int B) {
  const int lane = threadIdx.x & 63;
  const int wave = threadIdx.x >> 6;
  const int b = blockIdx.x * 4 + wave;
  if (b >= B) return;
  if (flags && flags[b] == 0) return;
  qr_f64_one(x, out, b, lane);
}

extern "C" void kernel_launch(void* const* d_in, const int* in_sizes, int n_in,
                              void* d_out, int out_size, void* d_ws,
                              size_t ws_size, hipStream_t stream) {
  const float* x = (const float*)d_in[0];
  float* out = (float*)d_out;
  const int B = in_sizes[0] / (Mrows * Rcols * 2);
  dim3 block(256);  // 4 waves -> 4 batch elements per block
  dim3 grid((B + 3) / 4);

  const size_t need_list = 16 + (size_t)B * sizeof(int);
  if (d_ws && ws_size >= need_list) {
    int* cnt = (int*)d_ws;
    int* list = (int*)d_ws + 4;  // 16-byte offset
    hipMemsetAsync(d_ws, 0, 16, stream);  // zero the worklist counter
    qr_house_f32<<<grid, block, 0, stream>>>(x, out, cnt, list, nullptr, B);
    qr_house_f64_list<<<dim3(512), block, 0, stream>>>(x, out, cnt, list);
  } else if (d_ws && ws_size >= (size_t)B) {
    unsigned char* flags = (unsigned char*)d_ws;
    qr_house_f32<<<grid, block, 0, stream>>>(x, out, nullptr, nullptr, flags, B);
    qr_house_f64_flags<<<grid, block, 0, stream>>>(x, out, flags, B);
  } else {
    qr_house_f64_flags<<<grid, block, 0, stream>>>(x, out, nullptr, B);
  }
}

// Round 3
// 687.203 us; speedup vs baseline: 2.6836x; 1.0500x over previous
//
#include <hip/hip_runtime.h>

// Batched complex QR (Householder, LAPACK clarfg/cgeqr2 convention).
// One batch element per wave; lane = matrix row (M=64 == wavefront size).
//
// v4 strategy:
//  * Round-2 post-mortem: f32 pass hit VALUBusy 98.8% but VGPR_Count=60 —
//    the >=64-float working set was AGPR-spilled under __launch_bounds__(256)'s
//    default occupancy target, inflating VALU issue ~2.7x (accvgpr shuffles).
//    Fix: __launch_bounds__(256, 1) lifts the VGPR budget to 512.
//  * FP32 factorization with pure-VALU wave reductions (4 DPP-fused adds +
//    permlane16_swap + permlane32_swap — zero DS ops). Raw v_sqrt_f32.
//    Q formed by triangular solve Q = A * R^-1 (readlane broadcasts).
//  * Sign robustness: batches where any |Re(alpha_i)| < 1e-3 go onto a
//    compacted worklist (atomicAdd) and are redone by the FP64 kernel
//    (~1.3% of batches). The FP64 path now also uses pure-VALU reductions
//    (DPP on 32-bit halves + v_add_f64) and readlane broadcasts — its
//    single-batch latency chain is ~4x shorter than the __shfl version.

constexpr int Mrows = 64;
constexpr int Rcols = 16;

typedef int v2i __attribute__((ext_vector_type(2)));

#if defined(__has_builtin)
#if __has_builtin(__builtin_amdgcn_permlane16_swap)
#define USE_PL16 1
#else
#define USE_PL16 0
#endif
#if __has_builtin(__builtin_amdgcn_permlane32_swap)
#define USE_PL32 1
#else
#define USE_PL32 0
#endif
#else
#define USE_PL16 0
#define USE_PL32 0
#endif

// ---------------- fp32 wave-64 sum-broadcast (pure VALU) ----------------
template <int CTRL>
__device__ __forceinline__ float dpp_fadd(float v) {
  int s = __builtin_amdgcn_update_dpp(0, __float_as_int(v), CTRL, 0xF, 0xF, true);
  return v + __int_as_float(s);
}

__device__ __forceinline__ float wsum64f_fast(float v, int bpa) {
  v = dpp_fadd<0xB1>(v);   // quad_perm [1,0,3,2]  : + lane^1
  v = dpp_fadd<0x4E>(v);   // quad_perm [2,3,0,1]  : + lane^2
  v = dpp_fadd<0x141>(v);  // row_half_mirror      : fold 8-group
  v = dpp_fadd<0x140>(v);  // row_mirror           : fold 16-group
#if USE_PL16
  {
    v2i r = __builtin_amdgcn_permlane16_swap(__float_as_int(v), __float_as_int(v),
                                             false, false);
    v = __int_as_float(r[0]) + __int_as_float(r[1]);  // + lane^16
  }
#else
  v += __int_as_float(__builtin_amdgcn_ds_swizzle(__float_as_int(v), 0x401F));
#endif
#if USE_PL32
  {
    v2i r = __builtin_amdgcn_permlane32_swap(__float_as_int(v), __float_as_int(v),
                                             false, false);
    v = __int_as_float(r[0]) + __int_as_float(r[1]);  // + lane^32
  }
#else
  v += __int_as_float(__builtin_amdgcn_ds_bpermute(bpa, __float_as_int(v)));
#endif
  return v;
}

__device__ __forceinline__ float rdlane(float v, int srclane) {
  return __int_as_float(__builtin_amdgcn_readlane(__float_as_int(v), srclane));
}

// ---------------- fp64 wave-64 sum-broadcast (pure VALU) ----------------
template <int CTRL>
__device__ __forceinline__ double dpp_dadd(double v) {
  union { double d; int i[2]; } u, s;
  u.d = v;
  s.i[0] = __builtin_amdgcn_update_dpp(0, u.i[0], CTRL, 0xF, 0xF, true);
  s.i[1] = __builtin_amdgcn_update_dpp(0, u.i[1], CTRL, 0xF, 0xF, true);
  return v + s.d;
}

__device__ __forceinline__ double plswap16_add_d(double v) {
#if USE_PL16
  union { double d; int i[2]; } u, a, b;
  u.d = v;
  v2i rlo = __builtin_amdgcn_permlane16_swap(u.i[0], u.i[0], false, false);
  v2i rhi = __builtin_amdgcn_permlane16_swap(u.i[1], u.i[1], false, false);
  a.i[0] = rlo[0]; a.i[1] = rhi[0];
  b.i[0] = rlo[1]; b.i[1] = rhi[1];
  return a.d + b.d;
#else
  return v + __shfl_xor(v, 16, 64);
#endif
}

__device__ __forceinline__ double plswap32_add_d(double v) {
#if USE_PL32
  union { double d; int i[2]; } u, a, b;
  u.d = v;
  v2i rlo = __builtin_amdgcn_permlane32_swap(u.i[0], u.i[0], false, false);
  v2i rhi = __builtin_amdgcn_permlane32_swap(u.i[1], u.i[1], false, false);
  a.i[0] = rlo[0]; a.i[1] = rhi[0];
  b.i[0] = rlo[1]; b.i[1] = rhi[1];
  return a.d + b.d;
#else
  return v + __shfl_xor(v, 32, 64);
#endif
}

__device__ __forceinline__ double wsum64d_fast(double v) {
  v = dpp_dadd<0xB1>(v);
  v = dpp_dadd<0x4E>(v);
  v = dpp_dadd<0x141>(v);
  v = dpp_dadd<0x140>(v);
  v = plswap16_add_d(v);
  v = plswap32_add_d(v);
  return v;
}

__device__ __forceinline__ double rdlaned(double v, int srclane) {
  union { double d; int i[2]; } u, r;
  u.d = v;
  r.i[0] = __builtin_amdgcn_readlane(u.i[0], srclane);
  r.i[1] = __builtin_amdgcn_readlane(u.i[1], srclane);
  return r.d;
}

// =====================================================================
// Pass 1: FP32 factorization + Q = A R^-1 solve. Risky batches -> worklist.
// =====================================================================
__global__ __launch_bounds__(256, 1) void qr_house_f32(
    const float* __restrict__ x, float* __restrict__ out,
    int* __restrict__ cnt, int* __restrict__ list,
    unsigned char* __restrict__ flags, int B) {
  const int lane = threadIdx.x & 63;
  const int wave = threadIdx.x >> 6;
  const int b = blockIdx.x * 4 + wave;
  if (b >= B) return;
  const int bpa = ((lane ^ 32) << 2);  // ds_bpermute fallback addr

  const float4* xp = reinterpret_cast<const float4*>(
      x + (size_t)b * (Mrows * Rcols * 2) + (size_t)lane * (Rcols * 2));
  float xr[Rcols], xi[Rcols];   // original A (becomes Q in the solve)
  float ar[Rcols], ai[Rcols];   // working copy -> R (upper) + reflectors
#pragma unroll
  for (int k = 0; k < Rcols / 2; ++k) {
    float4 t = xp[k];
    xr[2 * k] = t.x;  xi[2 * k] = t.y;
    xr[2 * k + 1] = t.z;  xi[2 * k + 1] = t.w;
  }
#pragma unroll
  for (int j = 0; j < Rcols; ++j) { ar[j] = xr[j]; ai[j] = xi[j]; }

  bool risky = false;

  // ---- cgeqr2 in fp32 (apply H_i^H = I - conj(tau) v v^H) ----
#pragma unroll
  for (int i = 0; i < Rcols; ++i) {
    float cr = ar[i], ci = ai[i];
    float sq = (lane > i) ? (cr * cr + ci * ci) : 0.0f;
    float xnorm2 = wsum64f_fast(sq, bpa);
    float alphr = rdlane(cr, i);
    float alphi = rdlane(ci, i);

    // Near-tie sign decision -> fp64 pass redoes this batch.
    risky = risky || (fabsf(alphr) < 1e-3f);

    float tr, ti;
    if (xnorm2 == 0.0f && alphi == 0.0f) {
      tr = 0.0f;  ti = 0.0f;
    } else {
      float nrm = __builtin_amdgcn_sqrtf(alphr * alphr + alphi * alphi + xnorm2);
      float beta = (alphr >= 0.0f) ? -nrm : nrm;  // -SIGN(nrm, alphr)
      float rb = __builtin_amdgcn_rcpf(beta);
      tr = (beta - alphr) * rb;
      ti = -alphi * rb;
      float dr = alphr - beta, di = alphi;
      float inv = __builtin_amdgcn_rcpf(dr * dr + di * di);
      float sr = dr * inv, si = -di * inv;
      if (lane > i) {  // v = x / (alpha - beta), stored below diagonal
        ar[i] = cr * sr - ci * si;
        ai[i] = cr * si + ci * sr;
      }
      if (lane == i) {  // R diagonal (real beta) for the solve
        ar[i] = beta;
        ai[i] = 0.0f;
      }
    }

    float vr = (lane == i) ? 1.0f : ((lane > i) ? ar[i] : 0.0f);
    float vi = (lane == i) ? 0.0f : ((lane > i) ? ai[i] : 0.0f);
    const float ctr = tr, cti = -ti;  // conj(tau)
#pragma unroll
    for (int j = i + 1; j < Rcols; ++j) {
      float pr = vr * ar[j] + vi * ai[j];
      float pi = vr * ai[j] - vi * ar[j];
      pr = wsum64f_fast(pr, bpa);
      pi = wsum64f_fast(pi, bpa);
      float wr = ctr * pr - cti * pi;
      float wi = ctr * pi + cti * pr;
      ar[j] -= wr * vr - wi * vi;
      ai[j] -= wr * vi + wi * vr;
    }
  }

  if (risky) {  // wave-uniform (alphr is broadcast)
    if (lane == 0) {
      if (cnt) {
        int idx = atomicAdd(cnt, 1);
        list[idx] = b;
      } else {
        flags[b] = 1;
      }
    }
    return;  // fp64 pass produces this batch's output
  }
  if (!cnt && lane == 0) flags[b] = 0;

  // ---- Q via triangular solve: Q[:,j] = (A[:,j] - sum_{k<j} Q[:,k] R[k,j]) / beta_j
#pragma unroll
  for (int j = 0; j < Rcols; ++j) {
    float wr = xr[j], wi = xi[j];
#pragma unroll
    for (int k = 0; k < j; ++k) {
      float rr = rdlane(ar[j], k);
      float ri = rdlane(ai[j], k);
      wr -= xr[k] * rr - xi[k] * ri;
      wi -= xr[k] * ri + xi[k] * rr;
    }
    float rb = __builtin_amdgcn_rcpf(rdlane(ar[j], j));  // beta_j is real
    xr[j] = wr * rb;
    xi[j] = wi * rb;
  }

  float4* op = reinterpret_cast<float4*>(
      out + (size_t)b * (Mrows * Rcols * 2) + (size_t)lane * (Rcols * 2));
#pragma unroll
  for (int k = 0; k < Rcols / 2; ++k) {
    op[k] = make_float4(xr[2 * k], xi[2 * k], xr[2 * k + 1], xi[2 * k + 1]);
  }
}

// =====================================================================
// FP64 redo: proven math, pure-VALU reductions, one batch per wave.
// =====================================================================
__device__ void qr_f64_one(const float* __restrict__ x,
                           float* __restrict__ out, int b, int lane, int bpa) {
  const float4* xp = reinterpret_cast<const float4*>(
      x + (size_t)b * (Mrows * Rcols * 2) + (size_t)lane * (Rcols * 2));
  double ar[Rcols], ai[Rcols];
#pragma unroll
  for (int k = 0; k < Rcols / 2; ++k) {
    float4 t = xp[k];
    ar[2 * k] = (double)t.x;
    ai[2 * k] = (double)t.y;
    ar[2 * k + 1] = (double)t.z;
    ai[2 * k + 1] = (double)t.w;
  }

  double taur[Rcols], taui[Rcols];

#pragma unroll
  for (int i = 0; i < Rcols; ++i) {
    double cr = ar[i], ci = ai[i];
    double sq = (lane > i) ? (cr * cr + ci * ci) : 0.0;
    double xnorm2 = wsum64d_fast(sq);
    double alphr = rdlaned(cr, i);
    double alphi = rdlaned(ci, i);

    double tr, ti;
    if (xnorm2 == 0.0 && alphi == 0.0) {
      tr = 0.0;
      ti = 0.0;
    } else {
      double nrm = sqrt(alphr * alphr + alphi * alphi + xnorm2);
      double beta = (alphr >= 0.0) ? -nrm : nrm;
      double rb = 1.0 / beta;
      tr = (beta - alphr) * rb;
      ti = -alphi * rb;
      double dr = alphr - beta, di = alphi;
      double inv = 1.0 / (dr * dr + di * di);
      double sr = dr * inv, si = -di * inv;
      if (lane > i) {
        double nr = cr * sr - ci * si;
        double ni = cr * si + ci * sr;
        ar[i] = nr;
        ai[i] = ni;
      }
    }
    taur[i] = tr;
    taui[i] = ti;

    double vr = (lane == i) ? 1.0 : ((lane > i) ? ar[i] : 0.0);
    double vi = (lane == i) ? 0.0 : ((lane > i) ? ai[i] : 0.0);
    const double ctr = tr, cti = -ti;
#pragma unroll
    for (int j = i + 1; j < Rcols; ++j) {
      double pr = vr * ar[j] + vi * ai[j];
      double pi = vr * ai[j] - vi * ar[j];
      pr = wsum64d_fast(pr);
      pi = wsum64d_fast(pi);
      double wr = ctr * pr - cti * pi;
      double wi = ctr * pi + cti * pr;
      ar[j] -= wr * vr - wi * vi;
      ai[j] -= wr * vi + wi * vr;
    }
  }

  float vfr[Rcols], vfi[Rcols], tfr[Rcols], tfi[Rcols];
#pragma unroll
  for (int i = 0; i < Rcols; ++i) {
    vfr[i] = (lane == i) ? 1.0f : ((lane > i) ? (float)ar[i] : 0.0f);
    vfi[i] = (lane == i) ? 0.0f : ((lane > i) ? (float)ai[i] : 0.0f);
    tfr[i] = (float)taur[i];
    tfi[i] = (float)taui[i];
  }

  float qre[Rcols], qim[Rcols];
#pragma unroll
  for (int i = Rcols - 1; i >= 0; --i) {
    const float tr = tfr[i], ti = tfi[i];
    const float vr = vfr[i], vi = vfi[i];
#pragma unroll
    for (int j = i + 1; j < Rcols; ++j) {
      float pr = vr * qre[j] + vi * qim[j];
      float pi = vr * qim[j] - vi * qre[j];
      pr = wsum64f_fast(pr, bpa);
      pi = wsum64f_fast(pi, bpa);
      float wr = tr * pr - ti * pi;
      float wi = tr * pi + ti * pr;
      qre[j] -= wr * vr - wi * vi;
      qim[j] -= wr * vi + wi * vr;
    }
    float dr = -(tr * vr - ti * vi);
    float di = -(tr * vi + ti * vr);
    if (lane == i) {
      dr = 1.0f - tr;
      di = -ti;
    }
    if (lane < i) {
      dr = 0.0f;
      di = 0.0f;
    }
    qre[i] = dr;
    qim[i] = di;
  }

  float4* op = reinterpret_cast<float4*>(
      out + (size_t)b * (Mrows * Rcols * 2) + (size_t)lane * (Rcols * 2));
#pragma unroll
  for (int k = 0; k < Rcols / 2; ++k) {
    op[k] = make_float4(qre[2 * k], qim[2 * k], qre[2 * k + 1], qim[2 * k + 1]);
  }
}

// Pass 2 (worklist mode): 2048 waves grid-stride over the compacted list.
__global__ __launch_bounds__(256, 1) void qr_house_f64_list(
    const float* __restrict__ x, float* __restrict__ out,
    const int* __restrict__ cnt, const int* __restrict__ list) {
  const int lane = threadIdx.x & 63;
  const int bpa = ((lane ^ 32) << 2);
  const int widx = blockIdx.x * 4 + (threadIdx.x >> 6);
  const int n = *cnt;
  for (int w = widx; w < n; w += 2048) {
    qr_f64_one(x, out, list[w], lane, bpa);
  }
}

// Pass 2 (flags fallback / full fallback).
__global__ __launch_bounds__(256, 1) void qr_house_f64_flags(
    const float* __restrict__ x, float* __restrict__ out,
    const unsigned char* __restrict__ flags, int B) {
  const int lane = threadIdx.x & 63;
  const int bpa = ((lane ^ 32) << 2);
  const int wave = threadIdx.x >> 6;
  const int b = blockIdx.x * 4 + wave;
  if (b >= B) return;
  if (flags && flags[b] == 0) return;
  qr_f64_one(x, out, b, lane, bpa);
}

extern "C" void kernel_launch(void* const* d_in, const int* in_sizes, int n_in,
                              void* d_out, int out_size, void* d_ws,
                              size_t ws_size, hipStream_t stream) {
  const float* x = (const float*)d_in[0];
  float* out = (float*)d_out;
  const int B = in_sizes[0] / (Mrows * Rcols * 2);
  dim3 block(256);  // 4 waves -> 4 batch elements per block
  dim3 grid((B + 3) / 4);

  const size_t need_list = 16 + (size_t)B * sizeof(int);
  if (d_ws && ws_size >= need_list) {
    int* cnt = (int*)d_ws;
    int* list = (int*)d_ws + 4;  // 16-byte offset
    hipMemsetAsync(d_ws, 0, 16, stream);  // zero the worklist counter
    qr_house_f32<<<grid, block, 0, stream>>>(x, out, cnt, list, nullptr, B);
    qr_house_f64_list<<<dim3(512), block, 0, stream>>>(x, out, cnt, list);
  } else if (d_ws && ws_size >= (size_t)B) {
    unsigned char* flags = (unsigned char*)d_ws;
    qr_house_f32<<<grid, block, 0, stream>>>(x, out, nullptr, nullptr, flags, B);
    qr_house_f64_flags<<<grid, block, 0, stream>>>(x, out, flags, B);
  } else {
    qr_house_f64_flags<<<grid, block, 0, stream>>>(x, out, nullptr, B);
  }
}